// Round 1
// baseline (384.521 us; speedup 1.0000x reference)
//
#include <hip/hip_runtime.h>

#define N_ENT 500000
#define N_REL 200
#define DIMS 128
#define BATCH 16384
#define MARGIN 1.0f

// ws layout (int32 element indexing):
// [0,200)              counts
// [256,457)            offsets (exclusive prefix, 201 entries)
// [512,712)            cursors
// 768                  float accumulator
// [1024, 1024+BATCH)   bucketed row ids, grouped by relation

__global__ void k_zero(int* wsi) {
    int t = blockIdx.x * blockDim.x + threadIdx.x;
    if (t < N_REL) { wsi[t] = 0; wsi[512 + t] = 0; }
    if (t == 0) reinterpret_cast<float*>(wsi)[768] = 0.0f;
}

__global__ void k_count(const int* __restrict__ data, int* wsi) {
    int b = blockIdx.x * blockDim.x + threadIdx.x;
    if (b < BATCH) atomicAdd(&wsi[data[b * 5 + 2]], 1);
}

__global__ void k_prefix(int* wsi) {
    if (threadIdx.x == 0 && blockIdx.x == 0) {
        int run = 0;
        for (int r = 0; r < N_REL; ++r) { wsi[256 + r] = run; run += wsi[r]; }
        wsi[256 + N_REL] = run;
    }
}

__global__ void k_scatter(const int* __restrict__ data, int* wsi) {
    int b = blockIdx.x * blockDim.x + threadIdx.x;
    if (b < BATCH) {
        int r = data[b * 5 + 2];
        int p = wsi[256 + r] + atomicAdd(&wsi[512 + r], 1);
        wsi[1024 + p] = b;
    }
}

__device__ __forceinline__ void fma4(float4& a, float s, const float4& b) {
    a.x = fmaf(s, b.x, a.x);
    a.y = fmaf(s, b.y, a.y);
    a.z = fmaf(s, b.z, a.z);
    a.w = fmaf(s, b.w, a.w);
}

// 400 WGs: blockIdx>>1 = relation, blockIdx&1 = which half of its bucket.
// Each lane holds a 16-row x 4-col tile of R in registers (16 float4).
// score contribution of lane = sum_{i in rows} h_i * (R4_i . t4)  with
// u4 = sum_i h_i * R4_i accumulated first (pure fmac), dotted with t4 at end.
__global__ void __launch_bounds__(256) k_main(const int* __restrict__ data,
                                              const float* __restrict__ ent,
                                              const float* __restrict__ rel,
                                              int* wsi) {
    __shared__ float4 sh[4][8][32];  // kind (h,t,ch,ct) x row-in-batch x float4
    __shared__ float parts[4][8];    // wave x row-in-batch

    const int tid  = threadIdx.x;
    const int c    = tid & 31;   // column float4 index (cols 4c..4c+3)
    const int rg   = tid >> 5;   // row group (rows 16*rg .. 16*rg+15)
    const int wave = tid >> 6;
    const int lane = tid & 63;

    const int r    = blockIdx.x >> 1;
    const int half = blockIdx.x & 1;
    const int bstart = wsi[256 + r];
    const int bend   = wsi[256 + r + 1];
    const int cnt_total = bend - bstart;
    if (cnt_total == 0) return;              // uniform exit, before barriers
    const int h1    = (cnt_total + 1) >> 1;
    const int start = bstart + (half ? h1 : 0);
    const int cnt   = half ? (cnt_total - h1) : h1;
    if (cnt <= 0) return;                    // uniform exit

    // Register-resident R tile: row rg*16+k, cols 4c..4c+3
    const float* Rg = rel + (size_t)r * (DIMS * DIMS);
    float4 Rr[16];
#pragma unroll
    for (int k = 0; k < 16; ++k)
        Rr[k] = *reinterpret_cast<const float4*>(Rg + (size_t)(rg * 16 + k) * DIMS + c * 4);

    const int* bucket = wsi + 1024;
    float wgacc = 0.0f;

    for (int b0 = 0; b0 < cnt; b0 += 8) {
        const int nv = min(8, cnt - b0);

        // Stage h,t,ch,ct for up to 8 rows: 1024 float4 loads, coalesced
        // 32 consecutive threads per 512B vector.
        for (int idx = tid; idx < 1024; idx += 256) {
            int f4   = idx & 31;
            int vid  = idx >> 5;
            int g    = vid >> 2;
            int kind = vid & 3;
            int gg   = (g < nv) ? g : (nv - 1);
            int b    = bucket[start + b0 + gg];
            int col  = (kind == 0) ? 0 : (kind == 1) ? 1 : (kind == 2) ? 3 : 4;
            int e    = data[b * 5 + col];
            sh[kind][g][f4] =
                *reinterpret_cast<const float4*>(ent + (size_t)e * DIMS + f4 * 4);
        }
        __syncthreads();

        for (int g = 0; g < 8; ++g) {
            float4 up = {0.f, 0.f, 0.f, 0.f};
            float4 un = {0.f, 0.f, 0.f, 0.f};
#pragma unroll
            for (int kk = 0; kk < 4; ++kk) {
                float4 h4 = sh[0][g][rg * 4 + kk];  // broadcast reads
                float4 g4 = sh[2][g][rg * 4 + kk];
                fma4(up, h4.x, Rr[kk * 4 + 0]);
                fma4(up, h4.y, Rr[kk * 4 + 1]);
                fma4(up, h4.z, Rr[kk * 4 + 2]);
                fma4(up, h4.w, Rr[kk * 4 + 3]);
                fma4(un, g4.x, Rr[kk * 4 + 0]);
                fma4(un, g4.y, Rr[kk * 4 + 1]);
                fma4(un, g4.z, Rr[kk * 4 + 2]);
                fma4(un, g4.w, Rr[kk * 4 + 3]);
            }
            float4 t4  = sh[1][g][c];
            float4 ct4 = sh[3][g][c];
            float s = up.x * t4.x + up.y * t4.y + up.z * t4.z + up.w * t4.w
                    - (un.x * ct4.x + un.y * ct4.y + un.z * ct4.z + un.w * ct4.w);
            // reduce over the 64-lane wave
            s += __shfl_xor(s, 32, 64);
            s += __shfl_xor(s, 16, 64);
            s += __shfl_xor(s, 8, 64);
            s += __shfl_xor(s, 4, 64);
            s += __shfl_xor(s, 2, 64);
            s += __shfl_xor(s, 1, 64);
            if (lane == 0) parts[wave][g] = s;
        }
        __syncthreads();

        if (tid < 8) {
            float v = parts[0][tid] + parts[1][tid] + parts[2][tid] + parts[3][tid]
                    + MARGIN;
            v = (tid < nv && v > 0.0f) ? v : 0.0f;
            v += __shfl_xor(v, 4, 64);
            v += __shfl_xor(v, 2, 64);
            v += __shfl_xor(v, 1, 64);
            if (tid == 0) wgacc += v;
        }
        __syncthreads();  // protect sh/parts before next batch restages
    }

    if (tid == 0) atomicAdd(&reinterpret_cast<float*>(wsi)[768], wgacc);
}

__global__ void k_final(const int* __restrict__ wsi, float* __restrict__ out) {
    if (threadIdx.x == 0 && blockIdx.x == 0)
        out[0] = reinterpret_cast<const float*>(wsi)[768] * (1.0f / (float)BATCH);
}

extern "C" void kernel_launch(void* const* d_in, const int* in_sizes, int n_in,
                              void* d_out, int out_size, void* d_ws, size_t ws_size,
                              hipStream_t stream) {
    const int*   data = (const int*)d_in[0];     // (BATCH,5) int32
    const float* ent  = (const float*)d_in[1];   // (N_ENT,128) f32
    const float* rel  = (const float*)d_in[2];   // (N_REL,128,128) f32
    float* out = (float*)d_out;
    int*   wsi = (int*)d_ws;

    k_zero<<<1, 256, 0, stream>>>(wsi);
    k_count<<<BATCH / 256, 256, 0, stream>>>(data, wsi);
    k_prefix<<<1, 64, 0, stream>>>(wsi);
    k_scatter<<<BATCH / 256, 256, 0, stream>>>(data, wsi);
    k_main<<<2 * N_REL, 256, 0, stream>>>(data, ent, rel, wsi);
    k_final<<<1, 64, 0, stream>>>(wsi, out);
}